// Round 14
// baseline (32.025 us; speedup 1.0000x reference)
//
#include <hip/hip_runtime.h>

// SemiPool2d max-plus: out[b,c,p,q] = max_{i<7,j<7}( x[b,c,2p+i,2q+j] + w[c,i,j] )
// x: (8,64,224,224) f32, w: (1,64,7,7) f32, out: (8,64,109,109) f32
//
// R11 structure (16-row band, 33KB LDS, 4 blocks/CU) + split-stage overlap:
//   issue DMA half1 (input rows 0..20, 5 instr/wave) + half2 (rows 21..36,
//   4 instr/wave), wave-blocked chunks -> uniform counts;
//   vmcnt(4) + barrier  -> waves 0,1 compute output rows p0..p0+7
//                          (inputs 0..20) while half2 is in flight;
//   vmcnt(0) + barrier  -> waves 2,3 compute rows p0+8..p0+15 (inputs 16..36).
// Same fetch, same LDS size, same compute mapping as R11 -> clean A/B on the
// overlap structure alone. Weights in SGPRs (bc blockIdx-derived).

#define HH 224
#define WW 224
#define HO 109
#define WO 109
#define CC 64
#define PBAND 16
#define NB 7
#define INROWS 37                   // 2*16+5
#define LDSF (INROWS*WW)            // 8288 floats = 33152 B
#define H1_PER_WAVE 294             // rows 0..20 = 1176 chunks / 4 waves
#define H1_INSTR 5                  // 4 full + 38-lane
#define H1_CHUNKS 1176
#define H2_PER_WAVE 224             // rows 21..36 = 896 chunks / 4 waves
#define H2_INSTR 4                  // 3 full + 32-lane

__global__ __launch_bounds__(256) void semipool_kernel(
    const float* __restrict__ x,
    const float* __restrict__ w,
    float* __restrict__ out)
{
    __shared__ float smem[LDSF];

    const int tid  = threadIdx.x;
    const int wv   = tid >> 6;
    const int lane = tid & 63;
    const int band = blockIdx.x >> 9;        // 0..6
    const int bc   = blockIdx.x & 511;       // scalar

    int p0b = band * PBAND;
    if (p0b > HO - PBAND) p0b = HO - PBAND;  // band 6 -> 93
    const int row0 = 2 * p0b;

    const float* src = x + (bc * HH + row0) * WW;

    // ---- issue half1: input rows 0..20 (wave-blocked, 5 instrs/wave) ----
#pragma unroll
    for (int it = 0; it < H1_INSTR; ++it) {
        int off = it * 64 + lane;
        if (off < H1_PER_WAVE) {
            int c = wv * H1_PER_WAVE + off;
            __builtin_amdgcn_global_load_lds(
                (const __attribute__((address_space(1))) void*)(src + 4 * c),
                (__attribute__((address_space(3))) void*)(smem + 4 * c),
                16, 0, 0);
        }
    }
    // ---- issue half2: input rows 21..36 (4 instrs/wave) ----
#pragma unroll
    for (int it = 0; it < H2_INSTR; ++it) {
        int off = it * 64 + lane;
        if (off < H2_PER_WAVE) {
            int c = H1_CHUNKS + wv * H2_PER_WAVE + off;
            __builtin_amdgcn_global_load_lds(
                (const __attribute__((address_space(1))) void*)(src + 4 * c),
                (__attribute__((address_space(3))) void*)(smem + 4 * c),
                16, 0, 0);
        }
    }

    // 49 channel weights -> SGPRs (uniform address; lgkmcnt, not vmcnt)
    const float* __restrict__ wp = w + (bc & (CC - 1)) * 49;
    float wr[49];
#pragma unroll
    for (int k = 0; k < 49; ++k) wr[k] = wp[k];

    // own 5 half1 instrs done (4 newest = half2 may be in flight)
    asm volatile("s_waitcnt vmcnt(4)" ::: "memory");
    __builtin_amdgcn_sched_barrier(0);
    __builtin_amdgcn_s_barrier();            // all waves' half1 staged
    __builtin_amdgcn_sched_barrier(0);

    int q = tid & 127; if (q > WO - 1) q = WO - 1;   // dups benign
    const int ph   = tid >> 7;                       // waves 0,1 / 2,3
    const int colb = 2 * q;

    float acc[8];
#pragma unroll
    for (int a = 0; a < 8; ++a) acc[a] = -1e30f;

#define COMPUTE(BASE)                                                     \
    do {                                                                  \
        _Pragma("unroll")                                                 \
        for (int r = 0; r < 21; ++r) {                                    \
            const float* lr = smem + ((BASE) + r) * WW + colb;            \
            float xr[8];                                                  \
            _Pragma("unroll")                                             \
            for (int k = 0; k < 4; ++k) {                                 \
                float2 v = *reinterpret_cast<const float2*>(lr + 2 * k);  \
                xr[2 * k] = v.x; xr[2 * k + 1] = v.y;                     \
            }                                                             \
            _Pragma("unroll")                                             \
            for (int pp = 0; pp < 8; ++pp) {                              \
                int i = r - 2 * pp;                                       \
                if (i >= 0 && i < 7) {                                    \
                    float s0 = xr[0] + wr[i * 7 + 0];                     \
                    float s1 = xr[1] + wr[i * 7 + 1];                     \
                    float s2 = xr[2] + wr[i * 7 + 2];                     \
                    float s3 = xr[3] + wr[i * 7 + 3];                     \
                    float s4 = xr[4] + wr[i * 7 + 4];                     \
                    float s5 = xr[5] + wr[i * 7 + 5];                     \
                    float s6 = xr[6] + wr[i * 7 + 6];                     \
                    float t0 = fmaxf(fmaxf(s0, s1), s2);                  \
                    float t1 = fmaxf(fmaxf(s3, s4), s5);                  \
                    float t2 = fmaxf(fmaxf(t0, t1), s6);                  \
                    acc[pp] = fmaxf(acc[pp], t2);                         \
                }                                                         \
            }                                                             \
        }                                                                 \
    } while (0)

    // phase A: waves 0,1 -> output rows p0..p0+7 (inputs 0..20, in half1)
    if (ph == 0) COMPUTE(0);

    asm volatile("s_waitcnt vmcnt(0)" ::: "memory");   // own half2 done
    __builtin_amdgcn_sched_barrier(0);
    __builtin_amdgcn_s_barrier();                      // all waves' half2 staged
    __builtin_amdgcn_sched_barrier(0);

    // phase B: waves 2,3 -> output rows p0+8..p0+15 (inputs 16..36)
    if (ph == 1) COMPUTE(16);

    // stores: ph0 stores right after barrier (overlaps ph1 compute)
    float* __restrict__ orow = out + (bc * HO + p0b + 8 * ph) * WO + q;
#pragma unroll
    for (int pp = 0; pp < 8; ++pp)
        orow[pp * WO] = acc[pp];
}

extern "C" void kernel_launch(void* const* d_in, const int* in_sizes, int n_in,
                              void* d_out, int out_size, void* d_ws, size_t ws_size,
                              hipStream_t stream) {
    const float* x = (const float*)d_in[0];
    const float* w = (const float*)d_in[1];
    float* out = (float*)d_out;

    semipool_kernel<<<NB * 512, 256, 0, stream>>>(x, w, out);
}

// Round 15
// 26.339 us; speedup vs baseline: 1.2159x; 1.2159x over previous
//
#include <hip/hip_runtime.h>

// SemiPool2d max-plus: out[b,c,p,q] = max_{i<7,j<7}( x[b,c,2p+i,2q+j] + w[c,i,j] )
// x: (8,64,224,224) f32, w: (1,64,7,7) f32, out: (8,64,109,109) f32
//
// R11 structure with PBAND=11: 27-row input band = 24.2 KB LDS ->
// 6 blocks/CU resident (145 KB), 24 waves/CU, 20 block-generations ->
// finer stage/compute interleave across blocks (attacks phase bunching).
// Staging via global_load_lds (zero-VGPR DMA), vmcnt(0)+barrier, weights in
// SGPRs, conflict-free stride-2 column compute (b64 hits all 32 banks
// evenly), coalesced stores. Band 9 clamped to p0=98; row p0+5 computed by
// both ph halves (identical values, benign).

#define HH 224
#define WW 224
#define HO 109
#define WO 109
#define CC 64
#define PBAND 11
#define NBANDS 10
#define INROWS 27                   // 2*11+5
#define LDSF (INROWS*WW)            // 6048 floats = 24192 B
#define WCH 378                     // 16B chunks per wave = 6048/4/4
#define NSTG 6                      // 5 full + 58-lane

__global__ __launch_bounds__(256) void semipool_kernel(
    const float* __restrict__ x,
    const float* __restrict__ w,
    float* __restrict__ out)
{
    __shared__ float smem[LDSF];

    const int tid  = threadIdx.x;
    const int wv   = tid >> 6;
    const int lane = tid & 63;
    const int band = blockIdx.x >> 9;        // 0..9
    const int bc   = blockIdx.x & 511;       // scalar

    int p0 = band * PBAND;
    if (p0 > HO - PBAND) p0 = HO - PBAND;    // band 9 -> 98
    const int row0 = 2 * p0;

    // ---- stage 27x224 floats into LDS (wave-blocked, 6 instrs/wave) ----
    const float* src = x + (bc * HH + row0) * WW;
#pragma unroll
    for (int it = 0; it < NSTG; ++it) {
        int off = it * 64 + lane;
        if (off < WCH) {
            int c = wv * WCH + off;
            __builtin_amdgcn_global_load_lds(
                (const __attribute__((address_space(1))) void*)(src + 4 * c),
                (__attribute__((address_space(3))) void*)(smem + 4 * c),
                16, 0, 0);
        }
    }

    // 49 channel weights -> SGPRs (uniform address; lgkmcnt, not vmcnt)
    const float* __restrict__ wp = w + (bc & (CC - 1)) * 49;
    float wr[49];
#pragma unroll
    for (int k = 0; k < 49; ++k) wr[k] = wp[k];

    asm volatile("s_waitcnt vmcnt(0)" ::: "memory");
    __builtin_amdgcn_sched_barrier(0);
    __builtin_amdgcn_s_barrier();            // band fully staged
    __builtin_amdgcn_sched_barrier(0);

    // ---- compute: thread = (q, p-half); 6 outputs in a column ----
    int q = tid & 127; if (q > WO - 1) q = WO - 1;   // dups benign
    const int ph   = tid >> 7;                       // 0/1 (wave-uniform)
    const int colb = 2 * q;
    const int rbase = 10 * ph;               // ph0: inputs 0..16, ph1: 10..26

    float acc[6];
#pragma unroll
    for (int a = 0; a < 6; ++a) acc[a] = -1e30f;

#pragma unroll
    for (int r = 0; r < 17; ++r) {           // local input rows for thread
        const float* lr = smem + (rbase + r) * WW + colb;
        float xr[8];
#pragma unroll
        for (int k = 0; k < 4; ++k) {
            float2 v = *reinterpret_cast<const float2*>(lr + 2 * k);
            xr[2 * k]     = v.x;
            xr[2 * k + 1] = v.y;
        }
#pragma unroll
        for (int pp = 0; pp < 6; ++pp) {
            int i = r - 2 * pp;              // compile-time after unroll
            if (i >= 0 && i < 7) {
                float s0 = xr[0] + wr[i * 7 + 0];
                float s1 = xr[1] + wr[i * 7 + 1];
                float s2 = xr[2] + wr[i * 7 + 2];
                float s3 = xr[3] + wr[i * 7 + 3];
                float s4 = xr[4] + wr[i * 7 + 4];
                float s5 = xr[5] + wr[i * 7 + 5];
                float s6 = xr[6] + wr[i * 7 + 6];
                float t0 = fmaxf(fmaxf(s0, s1), s2);   // v_max3
                float t1 = fmaxf(fmaxf(s3, s4), s5);   // v_max3
                float t2 = fmaxf(fmaxf(t0, t1), s6);   // v_max3
                acc[pp] = fmaxf(acc[pp], t2);
            }
        }
    }

    // outputs p0+5ph+pp (row p0+5 written by both halves, same value)
    float* __restrict__ orow = out + (bc * HO + p0 + 5 * ph) * WO + q;
#pragma unroll
    for (int pp = 0; pp < 6; ++pp)
        orow[pp * WO] = acc[pp];
}

extern "C" void kernel_launch(void* const* d_in, const int* in_sizes, int n_in,
                              void* d_out, int out_size, void* d_ws, size_t ws_size,
                              hipStream_t stream) {
    const float* x = (const float*)d_in[0];
    const float* w = (const float*)d_in[1];
    float* out = (float*)d_out;

    semipool_kernel<<<NBANDS * 512, 256, 0, stream>>>(x, w, out);
}

// Round 16
// 25.520 us; speedup vs baseline: 1.2549x; 1.0321x over previous
//
#include <hip/hip_runtime.h>

// SemiPool2d max-plus: out[b,c,p,q] = max_{i<7,j<7}( x[b,c,2p+i,2q+j] + w[c,i,j] )
// x: (8,64,224,224) f32, w: (1,64,7,7) f32, out: (8,64,109,109) f32
//
// R15 structure with PBAND=10: 25-row input band = 22.4 KB LDS ->
// 7 blocks/CU resident (156.8 KB), 28 waves/CU (87.5% occupancy).
// Staging via global_load_lds (zero-VGPR DMA), vmcnt(0)+barrier, weights in
// SGPRs, conflict-free stride-2 column compute, coalesced stores.
// 11 bands (band 10 clamps to p0=99; overlap rows rewritten with identical
// values, benign). Per thread: 5 outputs, 15 LDS rows; even ph split.

#define HH 224
#define WW 224
#define HO 109
#define WO 109
#define CC 64
#define PBAND 10
#define NBANDS 11
#define INROWS 25                   // 2*10+5
#define LDSF (INROWS*WW)            // 5600 floats = 22400 B
#define WCH 350                     // 16B chunks per wave = 5600/4/4
#define NSTG 6                      // 5 full + 30-lane

__global__ __launch_bounds__(256) void semipool_kernel(
    const float* __restrict__ x,
    const float* __restrict__ w,
    float* __restrict__ out)
{
    __shared__ float smem[LDSF];

    const int tid  = threadIdx.x;
    const int wv   = tid >> 6;
    const int lane = tid & 63;
    const int band = blockIdx.x >> 9;        // 0..10
    const int bc   = blockIdx.x & 511;       // scalar

    int p0 = band * PBAND;
    if (p0 > HO - PBAND) p0 = HO - PBAND;    // band 10 -> 99
    const int row0 = 2 * p0;

    // ---- stage 25x224 floats into LDS (wave-blocked, 6 instrs/wave) ----
    const float* src = x + (bc * HH + row0) * WW;
#pragma unroll
    for (int it = 0; it < NSTG; ++it) {
        int off = it * 64 + lane;
        if (off < WCH) {
            int c = wv * WCH + off;
            __builtin_amdgcn_global_load_lds(
                (const __attribute__((address_space(1))) void*)(src + 4 * c),
                (__attribute__((address_space(3))) void*)(smem + 4 * c),
                16, 0, 0);
        }
    }

    // 49 channel weights -> SGPRs (uniform address; lgkmcnt, not vmcnt)
    const float* __restrict__ wp = w + (bc & (CC - 1)) * 49;
    float wr[49];
#pragma unroll
    for (int k = 0; k < 49; ++k) wr[k] = wp[k];

    asm volatile("s_waitcnt vmcnt(0)" ::: "memory");
    __builtin_amdgcn_sched_barrier(0);
    __builtin_amdgcn_s_barrier();            // band fully staged
    __builtin_amdgcn_sched_barrier(0);

    // ---- compute: thread = (q, p-half); 5 outputs in a column ----
    int q = tid & 127; if (q > WO - 1) q = WO - 1;   // dups benign
    const int ph   = tid >> 7;                       // 0/1 (wave-uniform)
    const int colb = 2 * q;
    const int rbase = 10 * ph;               // ph0: inputs 0..14, ph1: 10..24

    float acc[5];
#pragma unroll
    for (int a = 0; a < 5; ++a) acc[a] = -1e30f;

#pragma unroll
    for (int r = 0; r < 15; ++r) {           // local input rows for thread
        const float* lr = smem + (rbase + r) * WW + colb;
        float xr[8];
#pragma unroll
        for (int k = 0; k < 4; ++k) {
            float2 v = *reinterpret_cast<const float2*>(lr + 2 * k);
            xr[2 * k]     = v.x;
            xr[2 * k + 1] = v.y;
        }
#pragma unroll
        for (int pp = 0; pp < 5; ++pp) {
            int i = r - 2 * pp;              // compile-time after unroll
            if (i >= 0 && i < 7) {
                float s0 = xr[0] + wr[i * 7 + 0];
                float s1 = xr[1] + wr[i * 7 + 1];
                float s2 = xr[2] + wr[i * 7 + 2];
                float s3 = xr[3] + wr[i * 7 + 3];
                float s4 = xr[4] + wr[i * 7 + 4];
                float s5 = xr[5] + wr[i * 7 + 5];
                float s6 = xr[6] + wr[i * 7 + 6];
                float t0 = fmaxf(fmaxf(s0, s1), s2);   // v_max3
                float t1 = fmaxf(fmaxf(s3, s4), s5);   // v_max3
                float t2 = fmaxf(fmaxf(t0, t1), s6);   // v_max3
                acc[pp] = fmaxf(acc[pp], t2);
            }
        }
    }

    // outputs p0 + 5*ph + pp  (even split, no duplicated row)
    float* __restrict__ orow = out + (bc * HO + p0 + 5 * ph) * WO + q;
#pragma unroll
    for (int pp = 0; pp < 5; ++pp)
        orow[pp * WO] = acc[pp];
}

extern "C" void kernel_launch(void* const* d_in, const int* in_sizes, int n_in,
                              void* d_out, int out_size, void* d_ws, size_t ws_size,
                              hipStream_t stream) {
    const float* x = (const float*)d_in[0];
    const float* w = (const float*)d_in[1];
    float* out = (float*)d_out;

    semipool_kernel<<<NBANDS * 512, 256, 0, stream>>>(x, w, out);
}